// Round 19
// baseline (38.688 us; speedup 1.0000x reference)
//
#include <hip/hip_runtime.h>
#include <hip/hip_bf16.h>

// Sizes fixed by setup_inputs()
#define N_EL   1024
#define N_UP   512
#define NNUC   256
#define DIM    256
#define EDIM   32
#define KTOT   8192              // NNUC * EDIM, GEMM K dimension
#define NKP    8                 // K-partitions (K=1024 each)

#define GAIN_F      1.7872135f          // 1/std(silu(N(0,1))), analytic
#define INV_SQRT2_F 0.7071067811865476f

typedef __attribute__((ext_vector_type(8))) short bf16x8;
typedef __attribute__((ext_vector_type(4))) short bf16x4;
typedef __attribute__((ext_vector_type(4))) float f32x4;

__device__ __forceinline__ short f2bf(float x) {
    union { __hip_bfloat16 h; short s; } u;
    u.h = __float2bfloat16(x);     // compiler pk-fuses pairs (v_cvt_pk_bf16_f32)
    return u.s;
}

// ---------------------------------------------------------------------------
// K0 prep (R18 body, unchanged)
// ---------------------------------------------------------------------------
__global__ __launch_bounds__(256) void prep_kernel(
    const float* __restrict__ up, const float* __restrict__ dn,
    const float* __restrict__ wedge,
    const float* __restrict__ w1, const float* __restrict__ w2,
    const float* __restrict__ elec,
    short* __restrict__ w1f, short* __restrict__ w2f,
    short* __restrict__ elecb, short* __restrict__ Tf)
{
    const int idx = (blockIdx.x << 8) + threadIdx.x;   // 0..524287

    if (idx < 65536) {
        { // W1/W2 -> B-frag bf16 (65536 each)
            const int b  = idx & 7;
            const int l  = (idx >> 3) & 63;
            const int q  = (idx >> 9) & 7;
            const int nt = idx >> 12;
            const int j  = (q << 5) + ((l >> 4) << 3) + b;
            const int d  = (nt << 4) + (l & 15);
            w1f[idx] = f2bf(w1[j * DIM + d]);
            w2f[idx] = f2bf(w2[j * DIM + d]);
        }
        { // elec -> row-major bf16, 4 elems/thread
            const f32x4 v = *(const f32x4*)(elec + (idx << 2));
            bf16x4 o;
            o[0] = f2bf(v[0]); o[1] = f2bf(v[1]);
            o[2] = f2bf(v[2]); o[3] = f2bf(v[3]);
            *(bf16x4*)(elecb + (idx << 2)) = o;
        }
    }

    { // T fragments: 2 spins x 262144 threads x 8 elements
        const int s   = idx >> 18;             // 0 = up, 1 = down
        const int rem = idx & 262143;
        const int kt  = rem >> 10;             // nucleus 0..255
        const int dt  = (rem >> 6) & 15;
        const int l   = rem & 63;
        const int d   = (dt << 4) + (l & 15);
        const int jb  = (l >> 4) << 3;         // j base
        const float* __restrict__ inp = s ? dn : up;
        const float iv = inp[kt * DIM + d];
        const float* __restrict__ wcol = wedge + d;
        bf16x8 o;
        #pragma unroll
        for (int b = 0; b < 8; ++b)
            o[b] = f2bf(iv * wcol[(jb + b) * DIM]);
        *(bf16x8*)(Tf + ((size_t)s << 21) + ((size_t)rem << 3)) = o;
    }
}

// ---------------------------------------------------------------------------
// K1 edge_gemm v6: R18 geometry/schedule with CACHE-POLLUTION CONTROL:
//  - A loads are NON-TEMPORAL (A is read exactly once; caching it evicts
//    the 4 MB Tf B-table from L2 -> B re-reads fall to L3).
//  - P stores are NON-TEMPORAL (8 MB write-allocate also evicts Tf).
//  - LOADB issued before LOAD_A each sub (vmcnt in-order: waiting on B
//    must not force completion of younger A prefetches).
// B (Tf) loads stay cacheable -> should now be L2-resident.
// ---------------------------------------------------------------------------
__global__ __launch_bounds__(512) void edge_gemm(
    const float* __restrict__ eemb,
    const short* __restrict__ Tf,
    float* __restrict__ P)             // [8][1024][256] f32 partials
{
    __shared__ short A_lds[2][4096];   // [buf][frag(8)*lane(64)*8] = 8 KB/buf

    const int tid  = threadIdx.x;
    const int w    = tid >> 6;          // 0..7
    const int lane = tid & 63;
    const int g    = lane >> 4;
    const int c    = lane & 15;
    const int kp   = blockIdx.x & 7;    // K-part
    const int rt   = blockIdx.x >> 3;   // row-tile 0..31
    const int rb   = rt << 5;           // 32 rows
    const int kb   = kp << 10;          // K-chunk base (1024 per part)

    const short* __restrict__ Tb = Tf + ((rb < N_UP) ? 0 : (1 << 21));

    const int f  = w;                   // staging frag = wave id
    const int r_ = f >> 2;
    const int q_ = f & 3;
    const float* __restrict__ Asrc = eemb
        + (size_t)(rb + (r_ << 4) + c) * KTOT
        + kb + (q_ << 5) + (g << 3);
    short* const Ad0 = &A_lds[0][(f << 9) + (lane << 3)];
    short* const Ad1 = &A_lds[1][(f << 9) + (lane << 3)];

    f32x4 sE_lo, sE_hi, sO_lo, sO_hi;   // depth-2 A stage regs (even/odd)
    bf16x8 bA[8], bB[8];                // B double-buffer

    auto LOAD_A = [&](int sub, f32x4& lo, f32x4& hi) {
        const f32x4* p = (const f32x4*)(Asrc + (sub << 7));
        lo = __builtin_nontemporal_load(p);        // nt: don't allocate in L2
        hi = __builtin_nontemporal_load(p + 1);
    };
    auto WRITE_A = [&](const f32x4& lo, const f32x4& hi, short* dst) {
        union { bf16x8 v; short s[8]; } o;
        o.s[0] = f2bf(lo[0]); o.s[1] = f2bf(lo[1]);
        o.s[2] = f2bf(lo[2]); o.s[3] = f2bf(lo[3]);
        o.s[4] = f2bf(hi[0]); o.s[5] = f2bf(hi[1]);
        o.s[6] = f2bf(hi[2]); o.s[7] = f2bf(hi[3]);
        *(bf16x8*)dst = o.v;
    };
    auto LOADB = [&](int sub, bf16x8 (&bd)[8]) {
        #pragma unroll
        for (int t = 0; t < 2; ++t) {
            const int ct = (w << 1) + t;
            #pragma unroll
            for (int q = 0; q < 4; ++q) {
                const int ktg = (kp << 5) + (sub << 2) + q;
                bd[(t << 2) + q] = *(const bf16x8*)(
                    Tb + (((((ktg << 4) + ct) << 6) + lane) << 3));
            }
        }
    };

    f32x4 acc[2][2] = {{{0.f,0.f,0.f,0.f},{0.f,0.f,0.f,0.f}},
                       {{0.f,0.f,0.f,0.f},{0.f,0.f,0.f,0.f}}};

    auto COMPUTE = [&](int buf, bf16x8 (&bc)[8]) {
        bf16x8 a[2][4];
        #pragma unroll
        for (int rr = 0; rr < 2; ++rr)
            #pragma unroll
            for (int q = 0; q < 4; ++q)
                a[rr][q] = *(const bf16x8*)(
                    &A_lds[buf][((((rr << 2) + q)) << 9) + (lane << 3)]);
        #pragma unroll
        for (int q = 0; q < 4; ++q) {
            acc[0][0] = __builtin_amdgcn_mfma_f32_16x16x32_bf16(a[0][q], bc[q],     acc[0][0], 0, 0, 0);
            acc[0][1] = __builtin_amdgcn_mfma_f32_16x16x32_bf16(a[0][q], bc[4 + q], acc[0][1], 0, 0, 0);
            acc[1][0] = __builtin_amdgcn_mfma_f32_16x16x32_bf16(a[1][q], bc[q],     acc[1][0], 0, 0, 0);
            acc[1][1] = __builtin_amdgcn_mfma_f32_16x16x32_bf16(a[1][q], bc[4 + q], acc[1][1], 0, 0, 0);
        }
    };

    // prologue: B(0) first, then A(0), A(1) in flight; write A(0)
    LOADB(0, bA);
    LOAD_A(0, sE_lo, sE_hi);
    LOAD_A(1, sO_lo, sO_hi);
    WRITE_A(sE_lo, sE_hi, Ad0);
    __syncthreads();

    #pragma unroll
    for (int sub = 0; sub < 8; ++sub) {
        if ((sub & 1) == 0) {
            if (sub + 1 < 8) LOADB(sub + 1, bB);
            if (sub + 2 < 8) LOAD_A(sub + 2, sE_lo, sE_hi);
            COMPUTE(0, bA);
            if (sub + 1 < 8) WRITE_A(sO_lo, sO_hi, Ad1);
        } else {
            if (sub + 1 < 8) LOADB(sub + 1, bA);
            if (sub + 2 < 8) LOAD_A(sub + 2, sO_lo, sO_hi);
            COMPUTE(1, bB);
            if (sub + 1 < 8) WRITE_A(sE_lo, sE_hi, Ad0);
        }
        if (sub < 7) {
            // counted-wait barrier: drain own LDS ops only; global loads
            // stay in flight across the barrier.
            asm volatile("s_waitcnt lgkmcnt(0)" ::: "memory");
            __builtin_amdgcn_s_barrier();
            __builtin_amdgcn_sched_barrier(0);
        }
    }

    // epilogue: write kp-partial non-temporally (P not read until reduce;
    // write-allocate would evict Tf from L2)
    float* __restrict__ Pp = P + ((size_t)kp << 18);
    #pragma unroll
    for (int rr = 0; rr < 2; ++rr)
        #pragma unroll
        for (int t = 0; t < 2; ++t) {
            const int ct = (w << 1) + t;
            #pragma unroll
            for (int j = 0; j < 4; ++j) {
                const int row = rb + (rr << 4) + (g << 2) + j;
                __builtin_nontemporal_store(acc[rr][t][j],
                    &Pp[(row << 8) + (ct << 4) + c]);
            }
        }
}

// ---------------------------------------------------------------------------
// K2 reduce: agg = s1 * sum_kp P[kp]   (coalesced f32x4, 8 partials)
// ---------------------------------------------------------------------------
__global__ __launch_bounds__(256) void reduce_kernel(
    const float* __restrict__ P,
    const float* __restrict__ s1p,
    float* __restrict__ agg)
{
    const int idx = (blockIdx.x << 8) + threadIdx.x;    // 0..65535
    const float s1 = *s1p;
    f32x4 s = {0.f, 0.f, 0.f, 0.f};
    #pragma unroll
    for (int kp = 0; kp < NKP; ++kp) {
        const f32x4 v = *(const f32x4*)(P + ((size_t)kp << 18) + (idx << 2));
        s[0] += v[0]; s[1] += v[1]; s[2] += v[2]; s[3] += v[3];
    }
    s[0] *= s1; s[1] *= s1; s[2] *= s1; s[3] *= s1;
    *(f32x4*)(agg + (idx << 2)) = s;
}

// ---------------------------------------------------------------------------
// K3 out (R18 body, unchanged)
// ---------------------------------------------------------------------------
__global__ __launch_bounds__(512) void out_kernel(
    const short* __restrict__ elecb,
    const short* __restrict__ w1f, const short* __restrict__ w2f,
    const float* __restrict__ elec, const float* __restrict__ agg,
    const float* __restrict__ norm,
    const float* __restrict__ b1, const float* __restrict__ b2,
    const float* __restrict__ s2p,
    float* __restrict__ outp)
{
    __shared__ short h_s[16][264];      // +8 pad -> 2-way banks (free)

    const int tid  = threadIdx.x;
    const int w    = tid >> 6;          // 0..7
    const int lane = tid & 63;
    const int g    = lane >> 4;
    const int c    = lane & 15;
    const int mt   = blockIdx.x >> 2;   // row-tile 0..63
    const int qd   = blockIdx.x & 3;    // quadrant 0..3
    const int mb   = mt << 4;           // 16 rows per row-tile

    const short* abase = elecb + ((mb + c) << 8) + (g << 3);
    bf16x8 a[8];
    #pragma unroll
    for (int q = 0; q < 8; ++q) a[q] = *(const bf16x8*)(abase + (q << 5));

    const float s2 = *s2p;

    // ---------------- gemm1 (all 16 col-tiles) ----------------
    #pragma unroll
    for (int t = 0; t < 2; ++t) {
        const int ct = (w << 1) + t;
        const short* bb = w1f + (ct << 12) + (lane << 3);
        bf16x8 b[8];
        #pragma unroll
        for (int q = 0; q < 8; ++q) b[q] = *(const bf16x8*)(bb + (q << 9));
        f32x4 acc = {0.f, 0.f, 0.f, 0.f};
        #pragma unroll
        for (int q = 0; q < 8; ++q)
            acc = __builtin_amdgcn_mfma_f32_16x16x32_bf16(a[q], b[q], acc, 0, 0, 0);

        const int n  = (ct << 4) + c;
        const float bv = b1[n];
        #pragma unroll
        for (int r = 0; r < 4; ++r) {
            const int mr = (g << 2) + r;            // 0..15 (C-frag row)
            const int m  = mb + mr;
            const float y = (acc[r] + bv + agg[(m << 8) + n] * norm[m]) * s2;
            const float sig = 1.f / (1.f + __expf(-y));
            h_s[mr][n] = f2bf(GAIN_F * y * sig);
        }
    }
    __syncthreads();

    // ---------------- gemm2 (this block's quadrant; waves 0..3) -------
    if (w < 4) {
        bf16x8 a2[8];                               // row = c, k = q*32+g*8+b
        #pragma unroll
        for (int q = 0; q < 8; ++q)
            a2[q] = *(const bf16x8*)(&h_s[c][(q << 5) + (g << 3)]);

        const int ct = (qd << 2) + w;               // col-tile 0..15, unique
        const short* bb = w2f + (ct << 12) + (lane << 3);
        bf16x8 b[8];
        #pragma unroll
        for (int q = 0; q < 8; ++q) b[q] = *(const bf16x8*)(bb + (q << 9));
        f32x4 acc = {0.f, 0.f, 0.f, 0.f};
        #pragma unroll
        for (int q = 0; q < 8; ++q)
            acc = __builtin_amdgcn_mfma_f32_16x16x32_bf16(a2[q], b[q], acc, 0, 0, 0);

        const int n  = (ct << 4) + c;
        const float bv = b2[n];
        #pragma unroll
        for (int r = 0; r < 4; ++r) {
            const int m = mb + (g << 2) + r;
            const float z = acc[r] + bv;
            const float sig = 1.f / (1.f + __expf(-z));
            const float o = GAIN_F * z * sig;
            outp[(m << 8) + n] = (elec[(m << 8) + n] + o) * INV_SQRT2_F;
        }
    }
}

// ---------------------------------------------------------------------------
extern "C" void kernel_launch(void* const* d_in, const int* in_sizes, int n_in,
                              void* d_out, int out_size, void* d_ws, size_t ws_size,
                              hipStream_t stream)
{
    const float* elec  = (const float*)d_in[0];
    const float* up    = (const float*)d_in[1];
    const float* dn    = (const float*)d_in[2];
    const float* eemb  = (const float*)d_in[3];
    // d_in[4] = contr: init-time only, unused at runtime
    const float* norm  = (const float*)d_in[5];
    const float* W1    = (const float*)d_in[6];
    const float* b1    = (const float*)d_in[7];
    const float* Wedge = (const float*)d_in[8];
    const float* W2    = (const float*)d_in[9];
    const float* b2    = (const float*)d_in[10];
    const float* s1    = (const float*)d_in[11];
    const float* s2    = (const float*)d_in[12];

    // ws layout (shorts): w1f 65536 | w2f 65536 | elecb 262144 |
    //   Tf 4194304 | P f32 8x262144 (8 MB) | agg f32 262144 (1 MB)
    short* sbase = (short*)d_ws;
    short* w1f   = sbase;
    short* w2f   = sbase + 65536;
    short* elecb = sbase + 131072;
    short* Tf    = sbase + 393216;
    float* P     = (float*)(sbase + 393216 + 4194304);
    float* agg   = P + (size_t)NKP * 262144;

    prep_kernel  <<<2048, 256, 0, stream>>>(up, dn, Wedge, W1, W2, elec,
                                            w1f, w2f, elecb, Tf);
    edge_gemm    <<<256, 512, 0, stream>>>(eemb, Tf, P);
    reduce_kernel<<<256, 256, 0, stream>>>(P, s1, agg);
    out_kernel   <<<256, 512, 0, stream>>>(elecb, w1f, w2f, elec, agg, norm,
                                           b1, b2, s2, (float*)d_out);
}

// Round 20
// 32.844 us; speedup vs baseline: 1.1779x; 1.1779x over previous
//
#include <hip/hip_runtime.h>
#include <hip/hip_bf16.h>

// Sizes fixed by setup_inputs()
#define N_EL   1024
#define N_UP   512
#define NNUC   256
#define DIM    256
#define EDIM   32
#define KTOT   8192              // NNUC * EDIM, GEMM K dimension
#define NKP    16                // K-partitions (K=512 each)

#define GAIN_F      1.7872135f          // 1/std(silu(N(0,1))), analytic
#define INV_SQRT2_F 0.7071067811865476f

typedef __attribute__((ext_vector_type(8))) short bf16x8;
typedef __attribute__((ext_vector_type(4))) short bf16x4;
typedef __attribute__((ext_vector_type(4))) float f32x4;

__device__ __forceinline__ short f2bf(float x) {
    union { __hip_bfloat16 h; short s; } u;
    u.h = __float2bfloat16(x);     // compiler pk-fuses pairs (v_cvt_pk_bf16_f32)
    return u.s;
}

// ---------------------------------------------------------------------------
// K0 prep (unchanged)
// ---------------------------------------------------------------------------
__global__ __launch_bounds__(256) void prep_kernel(
    const float* __restrict__ up, const float* __restrict__ dn,
    const float* __restrict__ wedge,
    const float* __restrict__ w1, const float* __restrict__ w2,
    const float* __restrict__ elec,
    short* __restrict__ w1f, short* __restrict__ w2f,
    short* __restrict__ elecb, short* __restrict__ Tf)
{
    const int idx = (blockIdx.x << 8) + threadIdx.x;   // 0..524287

    if (idx < 65536) {
        { // W1/W2 -> B-frag bf16 (65536 each)
            const int b  = idx & 7;
            const int l  = (idx >> 3) & 63;
            const int q  = (idx >> 9) & 7;
            const int nt = idx >> 12;
            const int j  = (q << 5) + ((l >> 4) << 3) + b;
            const int d  = (nt << 4) + (l & 15);
            w1f[idx] = f2bf(w1[j * DIM + d]);
            w2f[idx] = f2bf(w2[j * DIM + d]);
        }
        { // elec -> row-major bf16, 4 elems/thread
            const f32x4 v = *(const f32x4*)(elec + (idx << 2));
            bf16x4 o;
            o[0] = f2bf(v[0]); o[1] = f2bf(v[1]);
            o[2] = f2bf(v[2]); o[3] = f2bf(v[3]);
            *(bf16x4*)(elecb + (idx << 2)) = o;
        }
    }

    { // T fragments: 2 spins x 262144 threads x 8 elements
        const int s   = idx >> 18;             // 0 = up, 1 = down
        const int rem = idx & 262143;
        const int kt  = rem >> 10;             // nucleus 0..255
        const int dt  = (rem >> 6) & 15;
        const int l   = rem & 63;
        const int d   = (dt << 4) + (l & 15);
        const int jb  = (l >> 4) << 3;         // j base
        const float* __restrict__ inp = s ? dn : up;
        const float iv = inp[kt * DIM + d];
        const float* __restrict__ wcol = wedge + d;
        bf16x8 o;
        #pragma unroll
        for (int b = 0; b < 8; ++b)
            o[b] = f2bf(iv * wcol[(jb + b) * DIM]);
        *(bf16x8*)(Tf + ((size_t)s << 21) + ((size_t)rem << 3)) = o;
    }
}

// ---------------------------------------------------------------------------
// K1 edge_gemm v7: M=64 rows/block, NKP=16 -> total B traffic halves
// (128 -> 64 MB). 256 blocks x 512 threads (16 mt x 16 kp). 4 subs of
// K=128. A_lds 16 KB/buf dbuf; plain __syncthreads (R17's proven body).
// Per wave: 4 row-subtiles x 2 col-tiles (32 MFMA/sub, acc 8 x f32x4).
// Staging: thread stages frags w and w+8 (2 x 32B read, 2 x 16B LDS write).
// ---------------------------------------------------------------------------
__global__ __launch_bounds__(512) void edge_gemm(
    const float* __restrict__ eemb,
    const short* __restrict__ Tf,
    float* __restrict__ P)             // [16][1024][256] f32 partials
{
    __shared__ short A_lds[2][8192];   // [buf][frag(16)*lane(64)*8] = 16 KB/buf

    const int tid  = threadIdx.x;
    const int w    = tid >> 6;          // 0..7
    const int lane = tid & 63;
    const int g    = lane >> 4;
    const int c    = lane & 15;
    const int kp   = blockIdx.x & 15;   // K-part (XCD = kp % 8)
    const int mt   = blockIdx.x >> 4;   // M-tile 0..15
    const int rb   = mt << 6;           // 64 rows
    const int kb   = kp << 9;           // K-chunk base (512 per part)

    const short* __restrict__ Tb = Tf + ((rb < N_UP) ? 0 : (1 << 21));

    // staging roles: thread stages frag f0 = w (slot tid) and f1 = w+8
    // frag f = (rr = f>>2, q = f&3); row = rb + rr*16 + c; col = kb + q*32 + g*8
    const int f0 = w, f1 = w + 8;
    const float* __restrict__ Asrc0 = eemb
        + (size_t)(rb + ((f0 >> 2) << 4) + c) * KTOT + kb + ((f0 & 3) << 5) + (g << 3);
    const float* __restrict__ Asrc1 = eemb
        + (size_t)(rb + ((f1 >> 2) << 4) + c) * KTOT + kb + ((f1 & 3) << 5) + (g << 3);
    const int dst0 = (f0 << 9) + (lane << 3);
    const int dst1 = (f1 << 9) + (lane << 3);

    f32x4 s0_lo, s0_hi, s1_lo, s1_hi;   // stage regs (2 slots)
    bf16x8 bA[8], bB[8];                // B double-buffer

    auto STAGE_LOAD = [&](int sub) {
        const float* p0 = Asrc0 + (sub << 7);
        const float* p1 = Asrc1 + (sub << 7);
        s0_lo = *(const f32x4*)p0;  s0_hi = *(const f32x4*)(p0 + 4);
        s1_lo = *(const f32x4*)p1;  s1_hi = *(const f32x4*)(p1 + 4);
    };
    auto STAGE_WRITE = [&](int buf) {
        union { bf16x8 v; short s[8]; } o;
        o.s[0] = f2bf(s0_lo[0]); o.s[1] = f2bf(s0_lo[1]);
        o.s[2] = f2bf(s0_lo[2]); o.s[3] = f2bf(s0_lo[3]);
        o.s[4] = f2bf(s0_hi[0]); o.s[5] = f2bf(s0_hi[1]);
        o.s[6] = f2bf(s0_hi[2]); o.s[7] = f2bf(s0_hi[3]);
        *(bf16x8*)(&A_lds[buf][dst0]) = o.v;
        o.s[0] = f2bf(s1_lo[0]); o.s[1] = f2bf(s1_lo[1]);
        o.s[2] = f2bf(s1_lo[2]); o.s[3] = f2bf(s1_lo[3]);
        o.s[4] = f2bf(s1_hi[0]); o.s[5] = f2bf(s1_hi[1]);
        o.s[6] = f2bf(s1_hi[2]); o.s[7] = f2bf(s1_hi[3]);
        *(bf16x8*)(&A_lds[buf][dst1]) = o.v;
    };
    auto LOADB = [&](int sub, bf16x8 (&bd)[8]) {
        #pragma unroll
        for (int t = 0; t < 2; ++t) {
            const int ct = (w << 1) + t;
            #pragma unroll
            for (int q = 0; q < 4; ++q) {
                const int ktg = (kp << 4) + (sub << 2) + q;
                bd[(t << 2) + q] = *(const bf16x8*)(
                    Tb + (((((ktg << 4) + ct) << 6) + lane) << 3));
            }
        }
    };

    f32x4 acc[4][2];
    #pragma unroll
    for (int rr = 0; rr < 4; ++rr)
        #pragma unroll
        for (int t = 0; t < 2; ++t)
            acc[rr][t] = f32x4{0.f, 0.f, 0.f, 0.f};

    auto COMPUTE = [&](int buf, bf16x8 (&bc)[8]) {
        #pragma unroll
        for (int rr = 0; rr < 4; ++rr) {
            #pragma unroll
            for (int q = 0; q < 4; ++q) {
                const bf16x8 a = *(const bf16x8*)(
                    &A_lds[buf][((((rr << 2) + q)) << 9) + (lane << 3)]);
                acc[rr][0] = __builtin_amdgcn_mfma_f32_16x16x32_bf16(a, bc[q],     acc[rr][0], 0, 0, 0);
                acc[rr][1] = __builtin_amdgcn_mfma_f32_16x16x32_bf16(a, bc[4 + q], acc[rr][1], 0, 0, 0);
            }
        }
    };

    // prologue
    STAGE_LOAD(0);
    LOADB(0, bA);
    STAGE_WRITE(0);
    __syncthreads();

    #pragma unroll
    for (int sub = 0; sub < 4; ++sub) {
        if ((sub & 1) == 0) {
            if (sub < 3) { STAGE_LOAD(sub + 1); LOADB(sub + 1, bB); }
            COMPUTE(0, bA);
            if (sub < 3) STAGE_WRITE(1);
        } else {
            if (sub < 3) { STAGE_LOAD(sub + 1); LOADB(sub + 1, bA); }
            COMPUTE(1, bB);
            if (sub < 3) STAGE_WRITE(0);
        }
        __syncthreads();
    }

    // epilogue: write kp-partial (C-frag: row = 4g+j, col = c)
    float* __restrict__ Pp = P + ((size_t)kp << 18);
    #pragma unroll
    for (int rr = 0; rr < 4; ++rr)
        #pragma unroll
        for (int t = 0; t < 2; ++t) {
            const int ct = (w << 1) + t;
            #pragma unroll
            for (int j = 0; j < 4; ++j) {
                const int row = rb + (rr << 4) + (g << 2) + j;
                Pp[(row << 8) + (ct << 4) + c] = acc[rr][t][j];
            }
        }
}

// ---------------------------------------------------------------------------
// K2 reduce: agg = s1 * sum_kp P[kp]   (coalesced f32x4, 16 partials)
// ---------------------------------------------------------------------------
__global__ __launch_bounds__(256) void reduce_kernel(
    const float* __restrict__ P,
    const float* __restrict__ s1p,
    float* __restrict__ agg)
{
    const int idx = (blockIdx.x << 8) + threadIdx.x;    // 0..65535
    const float s1 = *s1p;
    f32x4 s = {0.f, 0.f, 0.f, 0.f};
    #pragma unroll
    for (int kp = 0; kp < NKP; ++kp) {
        const f32x4 v = *(const f32x4*)(P + ((size_t)kp << 18) + (idx << 2));
        s[0] += v[0]; s[1] += v[1]; s[2] += v[2]; s[3] += v[3];
    }
    s[0] *= s1; s[1] *= s1; s[2] *= s1; s[3] *= s1;
    *(f32x4*)(agg + (idx << 2)) = s;
}

// ---------------------------------------------------------------------------
// K3 out (unchanged)
// ---------------------------------------------------------------------------
__global__ __launch_bounds__(512) void out_kernel(
    const short* __restrict__ elecb,
    const short* __restrict__ w1f, const short* __restrict__ w2f,
    const float* __restrict__ elec, const float* __restrict__ agg,
    const float* __restrict__ norm,
    const float* __restrict__ b1, const float* __restrict__ b2,
    const float* __restrict__ s2p,
    float* __restrict__ outp)
{
    __shared__ short h_s[16][264];      // +8 pad -> 2-way banks (free)

    const int tid  = threadIdx.x;
    const int w    = tid >> 6;          // 0..7
    const int lane = tid & 63;
    const int g    = lane >> 4;
    const int c    = lane & 15;
    const int mt   = blockIdx.x >> 2;   // row-tile 0..63
    const int qd   = blockIdx.x & 3;    // quadrant 0..3
    const int mb   = mt << 4;           // 16 rows per row-tile

    const short* abase = elecb + ((mb + c) << 8) + (g << 3);
    bf16x8 a[8];
    #pragma unroll
    for (int q = 0; q < 8; ++q) a[q] = *(const bf16x8*)(abase + (q << 5));

    const float s2 = *s2p;

    // ---------------- gemm1 (all 16 col-tiles) ----------------
    #pragma unroll
    for (int t = 0; t < 2; ++t) {
        const int ct = (w << 1) + t;
        const short* bb = w1f + (ct << 12) + (lane << 3);
        bf16x8 b[8];
        #pragma unroll
        for (int q = 0; q < 8; ++q) b[q] = *(const bf16x8*)(bb + (q << 9));
        f32x4 acc = {0.f, 0.f, 0.f, 0.f};
        #pragma unroll
        for (int q = 0; q < 8; ++q)
            acc = __builtin_amdgcn_mfma_f32_16x16x32_bf16(a[q], b[q], acc, 0, 0, 0);

        const int n  = (ct << 4) + c;
        const float bv = b1[n];
        #pragma unroll
        for (int r = 0; r < 4; ++r) {
            const int mr = (g << 2) + r;            // 0..15 (C-frag row)
            const int m  = mb + mr;
            const float y = (acc[r] + bv + agg[(m << 8) + n] * norm[m]) * s2;
            const float sig = 1.f / (1.f + __expf(-y));
            h_s[mr][n] = f2bf(GAIN_F * y * sig);
        }
    }
    __syncthreads();

    // ---------------- gemm2 (this block's quadrant; waves 0..3) -------
    if (w < 4) {
        bf16x8 a2[8];                               // row = c, k = q*32+g*8+b
        #pragma unroll
        for (int q = 0; q < 8; ++q)
            a2[q] = *(const bf16x8*)(&h_s[c][(q << 5) + (g << 3)]);

        const int ct = (qd << 2) + w;               // col-tile 0..15, unique
        const short* bb = w2f + (ct << 12) + (lane << 3);
        bf16x8 b[8];
        #pragma unroll
        for (int q = 0; q < 8; ++q) b[q] = *(const bf16x8*)(bb + (q << 9));
        f32x4 acc = {0.f, 0.f, 0.f, 0.f};
        #pragma unroll
        for (int q = 0; q < 8; ++q)
            acc = __builtin_amdgcn_mfma_f32_16x16x32_bf16(a2[q], b[q], acc, 0, 0, 0);

        const int n  = (ct << 4) + c;
        const float bv = b2[n];
        #pragma unroll
        for (int r = 0; r < 4; ++r) {
            const int m = mb + (g << 2) + r;
            const float z = acc[r] + bv;
            const float sig = 1.f / (1.f + __expf(-z));
            const float o = GAIN_F * z * sig;
            outp[(m << 8) + n] = (elec[(m << 8) + n] + o) * INV_SQRT2_F;
        }
    }
}

// ---------------------------------------------------------------------------
extern "C" void kernel_launch(void* const* d_in, const int* in_sizes, int n_in,
                              void* d_out, int out_size, void* d_ws, size_t ws_size,
                              hipStream_t stream)
{
    const float* elec  = (const float*)d_in[0];
    const float* up    = (const float*)d_in[1];
    const float* dn    = (const float*)d_in[2];
    const float* eemb  = (const float*)d_in[3];
    // d_in[4] = contr: init-time only, unused at runtime
    const float* norm  = (const float*)d_in[5];
    const float* W1    = (const float*)d_in[6];
    const float* b1    = (const float*)d_in[7];
    const float* Wedge = (const float*)d_in[8];
    const float* W2    = (const float*)d_in[9];
    const float* b2    = (const float*)d_in[10];
    const float* s1    = (const float*)d_in[11];
    const float* s2    = (const float*)d_in[12];

    // ws layout (shorts): w1f 65536 | w2f 65536 | elecb 262144 |
    //   Tf 4194304 | P f32 16x262144 (16 MB) | agg f32 262144 (1 MB)
    short* sbase = (short*)d_ws;
    short* w1f   = sbase;
    short* w2f   = sbase + 65536;
    short* elecb = sbase + 131072;
    short* Tf    = sbase + 393216;
    float* P     = (float*)(sbase + 393216 + 4194304);
    float* agg   = P + (size_t)NKP * 262144;

    prep_kernel  <<<2048, 256, 0, stream>>>(up, dn, Wedge, W1, W2, elec,
                                            w1f, w2f, elecb, Tf);
    edge_gemm    <<<256, 512, 0, stream>>>(eemb, Tf, P);
    reduce_kernel<<<256, 256, 0, stream>>>(P, s1, agg);
    out_kernel   <<<256, 512, 0, stream>>>(elecb, w1f, w2f, elec, agg, norm,
                                           b1, b2, s2, (float*)d_out);
}

// Round 21
// 31.784 us; speedup vs baseline: 1.2172x; 1.0334x over previous
//
#include <hip/hip_runtime.h>
#include <hip/hip_bf16.h>

// Sizes fixed by setup_inputs()
#define N_EL   1024
#define N_UP   512
#define NNUC   256
#define DIM    256
#define EDIM   32
#define KTOT   8192              // NNUC * EDIM, GEMM K dimension
#define NKP    8                 // K-partitions (K=1024 each)

#define GAIN_F      1.7872135f          // 1/std(silu(N(0,1))), analytic
#define INV_SQRT2_F 0.7071067811865476f

typedef __attribute__((ext_vector_type(8))) short bf16x8;
typedef __attribute__((ext_vector_type(4))) short bf16x4;
typedef __attribute__((ext_vector_type(4))) float f32x4;

typedef const __attribute__((address_space(1))) float GFloat;
typedef __attribute__((address_space(3))) float LFloat;

__device__ __forceinline__ short f2bf(float x) {
    union { __hip_bfloat16 h; short s; } u;
    u.h = __float2bfloat16(x);     // compiler pk-fuses pairs (v_cvt_pk_bf16_f32)
    return u.s;
}

// ---------------------------------------------------------------------------
// K0 prep (R17 body, unchanged)
// ---------------------------------------------------------------------------
__global__ __launch_bounds__(256) void prep_kernel(
    const float* __restrict__ up, const float* __restrict__ dn,
    const float* __restrict__ wedge,
    const float* __restrict__ w1, const float* __restrict__ w2,
    const float* __restrict__ elec,
    short* __restrict__ w1f, short* __restrict__ w2f,
    short* __restrict__ elecb, short* __restrict__ Tf)
{
    const int idx = (blockIdx.x << 8) + threadIdx.x;   // 0..524287

    if (idx < 65536) {
        { // W1/W2 -> B-frag bf16 (65536 each)
            const int b  = idx & 7;
            const int l  = (idx >> 3) & 63;
            const int q  = (idx >> 9) & 7;
            const int nt = idx >> 12;
            const int j  = (q << 5) + ((l >> 4) << 3) + b;
            const int d  = (nt << 4) + (l & 15);
            w1f[idx] = f2bf(w1[j * DIM + d]);
            w2f[idx] = f2bf(w2[j * DIM + d]);
        }
        { // elec -> row-major bf16, 4 elems/thread
            const f32x4 v = *(const f32x4*)(elec + (idx << 2));
            bf16x4 o;
            o[0] = f2bf(v[0]); o[1] = f2bf(v[1]);
            o[2] = f2bf(v[2]); o[3] = f2bf(v[3]);
            *(bf16x4*)(elecb + (idx << 2)) = o;
        }
    }

    { // T fragments: 2 spins x 262144 threads x 8 elements
        const int s   = idx >> 18;             // 0 = up, 1 = down
        const int rem = idx & 262143;
        const int kt  = rem >> 10;             // nucleus 0..255
        const int dt  = (rem >> 6) & 15;
        const int l   = rem & 63;
        const int d   = (dt << 4) + (l & 15);
        const int jb  = (l >> 4) << 3;         // j base
        const float* __restrict__ inp = s ? dn : up;
        const float iv = inp[kt * DIM + d];
        const float* __restrict__ wcol = wedge + d;
        bf16x8 o;
        #pragma unroll
        for (int b = 0; b < 8; ++b)
            o[b] = f2bf(iv * wcol[(jb + b) * DIM]);
        *(bf16x8*)(Tf + ((size_t)s << 21) + ((size_t)rem << 3)) = o;
    }
}

// ---------------------------------------------------------------------------
// K1 edge_gemm v8: A staged via global_load_lds (width=16, no VGPR dest ->
// no compiler-inserted vmcnt waits), f32 in LDS, cvt at consume.
// 3-buf LDS rotation: gloads for sub+2 stay in flight across raw s_barrier
// (no vmcnt(0) drain). gA(s) is retired implicitly by the compiler's
// counted wait on B(s-1) registers at sub s-1 (in-order vmcnt retirement),
// BEFORE that sub's barrier -> buf s%3 is complete when read at sub s.
// LDS layout: a[f][lane][8 f32] (f = frag rr*4+q); chunk ch=f*2+h is 1 KB
// written linearly (lane*16) with source-permuted global addresses.
// ---------------------------------------------------------------------------
__global__ __launch_bounds__(512) void edge_gemm(
    const float* __restrict__ eemb,
    const short* __restrict__ Tf,
    float* __restrict__ P)             // [8][1024][256] f32 partials
{
    __shared__ float A_lds[3][4096];   // 3 bufs x 16 KB = 48 KB

    const int tid  = threadIdx.x;
    const int w    = tid >> 6;          // 0..7
    const int lane = tid & 63;
    const int g    = lane >> 4;
    const int c    = lane & 15;
    const int kp   = blockIdx.x & 7;    // K-part (XCD round-robin)
    const int rt   = blockIdx.x >> 3;   // row-tile 0..31
    const int rb   = rt << 5;           // 32 rows
    const int kb   = kp << 10;          // K-chunk base (1024 per part)

    const short* __restrict__ Tb = Tf + ((rb < N_UP) ? 0 : (1 << 21));

    // staging: wave w owns chunks 2w, 2w+1. Chunk ch = f*2+h covers LDS
    // bytes [ch*1024, ch*1024+1024) written as lane*16; source lane l maps
    // to target (l' = h*32 + l/2, e0 = (l&1)*4) of frag f:
    //   row = rb + (f>>2)*16 + (l'&15)
    //   k   = kb + sub*128 + (f&3)*32 + (l'>>4)*8 + e0
    auto srcaddr = [&](int ch) -> const float* {
        const int fq  = ch >> 1;
        const int row = rb + ((fq >> 2) << 4) + ((lane >> 1) & 15);
        const int koff = ((fq & 3) << 5)
                       + ((((ch & 1) << 1) + (lane >> 5)) << 3)
                       + ((lane & 1) << 2);
        return eemb + (size_t)row * KTOT + kb + koff;
    };
    const float* gsrc0 = srcaddr((w << 1));
    const float* gsrc1 = srcaddr((w << 1) + 1);
    const int ldsoff0 = (w << 1) << 8;        // chunk*256 floats
    const int ldsoff1 = ((w << 1) + 1) << 8;

    auto GLOAD = [&](int sub, int buf) {
        __builtin_amdgcn_global_load_lds(
            (GFloat*)(gsrc0 + (sub << 7)), (LFloat*)(&A_lds[buf][ldsoff0]),
            16, 0, 0);
        __builtin_amdgcn_global_load_lds(
            (GFloat*)(gsrc1 + (sub << 7)), (LFloat*)(&A_lds[buf][ldsoff1]),
            16, 0, 0);
    };

    bf16x8 bA[8], bB[8];                // B double-buffer (VGPR)
    auto LOADB = [&](int sub, bf16x8 (&bd)[8]) {
        #pragma unroll
        for (int t = 0; t < 2; ++t) {
            const int ct = (w << 1) + t;
            #pragma unroll
            for (int q = 0; q < 4; ++q) {
                const int ktg = (kp << 5) + (sub << 2) + q;
                bd[(t << 2) + q] = *(const bf16x8*)(
                    Tb + (((((ktg << 4) + ct) << 6) + lane) << 3));
            }
        }
    };

    f32x4 acc[2][2] = {{{0.f,0.f,0.f,0.f},{0.f,0.f,0.f,0.f}},
                       {{0.f,0.f,0.f,0.f},{0.f,0.f,0.f,0.f}}};

    auto COMPUTE = [&](const float* Ab, bf16x8 (&bc)[8]) {
        #pragma unroll
        for (int rr = 0; rr < 2; ++rr) {
            #pragma unroll
            for (int q = 0; q < 4; ++q) {
                const int fq = (rr << 2) + q;
                const f32x4 lo = *(const f32x4*)(Ab + (fq << 9) + (lane << 3));
                const f32x4 hi = *(const f32x4*)(Ab + (fq << 9) + (lane << 3) + 4);
                union { bf16x8 v; short s[8]; } fa;
                fa.s[0] = f2bf(lo[0]); fa.s[1] = f2bf(lo[1]);
                fa.s[2] = f2bf(lo[2]); fa.s[3] = f2bf(lo[3]);
                fa.s[4] = f2bf(hi[0]); fa.s[5] = f2bf(hi[1]);
                fa.s[6] = f2bf(hi[2]); fa.s[7] = f2bf(hi[3]);
                acc[rr][0] = __builtin_amdgcn_mfma_f32_16x16x32_bf16(fa.v, bc[q],     acc[rr][0], 0, 0, 0);
                acc[rr][1] = __builtin_amdgcn_mfma_f32_16x16x32_bf16(fa.v, bc[4 + q], acc[rr][1], 0, 0, 0);
            }
        }
    };

    // prologue: gA(0), gA(1) in flight; B(0) to regs; drain gloads; barrier
    GLOAD(0, 0);
    GLOAD(1, 1);
    LOADB(0, bA);
    asm volatile("s_waitcnt vmcnt(8)");   // outstanding 12 -> 8: drains the 4 gloads
    __builtin_amdgcn_s_barrier();
    __builtin_amdgcn_sched_barrier(0);

    #pragma unroll
    for (int sub = 0; sub < 8; ++sub) {
        const int buf = sub % 3;          // compile-time after full unroll
        if (sub + 2 < 8) GLOAD(sub + 2, (sub + 2) % 3);
        if (sub + 1 < 8) { if (sub & 1) LOADB(sub + 1, bA); else LOADB(sub + 1, bB); }
        if (sub & 1) COMPUTE(A_lds[buf], bB); else COMPUTE(A_lds[buf], bA);
        if (sub < 7) {
            __builtin_amdgcn_sched_barrier(0);
            __builtin_amdgcn_s_barrier();
            __builtin_amdgcn_sched_barrier(0);
        }
    }

    // epilogue: write kp-partial (C-frag: row = 4g+j, col = c)
    float* __restrict__ Pp = P + ((size_t)kp << 18);
    #pragma unroll
    for (int rr = 0; rr < 2; ++rr)
        #pragma unroll
        for (int t = 0; t < 2; ++t) {
            const int ct = (w << 1) + t;
            #pragma unroll
            for (int j = 0; j < 4; ++j) {
                const int row = rb + (rr << 4) + (g << 2) + j;
                Pp[(row << 8) + (ct << 4) + c] = acc[rr][t][j];
            }
        }
}

// ---------------------------------------------------------------------------
// K2 reduce: agg = s1 * sum_kp P[kp]   (coalesced f32x4, 8 partials)
// ---------------------------------------------------------------------------
__global__ __launch_bounds__(256) void reduce_kernel(
    const float* __restrict__ P,
    const float* __restrict__ s1p,
    float* __restrict__ agg)
{
    const int idx = (blockIdx.x << 8) + threadIdx.x;    // 0..65535
    const float s1 = *s1p;
    f32x4 s = {0.f, 0.f, 0.f, 0.f};
    #pragma unroll
    for (int kp = 0; kp < NKP; ++kp) {
        const f32x4 v = *(const f32x4*)(P + ((size_t)kp << 18) + (idx << 2));
        s[0] += v[0]; s[1] += v[1]; s[2] += v[2]; s[3] += v[3];
    }
    s[0] *= s1; s[1] *= s1; s[2] *= s1; s[3] *= s1;
    *(f32x4*)(agg + (idx << 2)) = s;
}

// ---------------------------------------------------------------------------
// K3 out (R17 body, unchanged)
// ---------------------------------------------------------------------------
__global__ __launch_bounds__(512) void out_kernel(
    const short* __restrict__ elecb,
    const short* __restrict__ w1f, const short* __restrict__ w2f,
    const float* __restrict__ elec, const float* __restrict__ agg,
    const float* __restrict__ norm,
    const float* __restrict__ b1, const float* __restrict__ b2,
    const float* __restrict__ s2p,
    float* __restrict__ outp)
{
    __shared__ short h_s[16][264];      // +8 pad -> 2-way banks (free)

    const int tid  = threadIdx.x;
    const int w    = tid >> 6;          // 0..7
    const int lane = tid & 63;
    const int g    = lane >> 4;
    const int c    = lane & 15;
    const int mt   = blockIdx.x >> 2;   // row-tile 0..63
    const int qd   = blockIdx.x & 3;    // quadrant 0..3
    const int mb   = mt << 4;           // 16 rows per row-tile

    const short* abase = elecb + ((mb + c) << 8) + (g << 3);
    bf16x8 a[8];
    #pragma unroll
    for (int q = 0; q < 8; ++q) a[q] = *(const bf16x8*)(abase + (q << 5));

    const float s2 = *s2p;

    // ---------------- gemm1 (all 16 col-tiles) ----------------
    #pragma unroll
    for (int t = 0; t < 2; ++t) {
        const int ct = (w << 1) + t;
        const short* bb = w1f + (ct << 12) + (lane << 3);
        bf16x8 b[8];
        #pragma unroll
        for (int q = 0; q < 8; ++q) b[q] = *(const bf16x8*)(bb + (q << 9));
        f32x4 acc = {0.f, 0.f, 0.f, 0.f};
        #pragma unroll
        for (int q = 0; q < 8; ++q)
            acc = __builtin_amdgcn_mfma_f32_16x16x32_bf16(a[q], b[q], acc, 0, 0, 0);

        const int n  = (ct << 4) + c;
        const float bv = b1[n];
        #pragma unroll
        for (int r = 0; r < 4; ++r) {
            const int mr = (g << 2) + r;            // 0..15 (C-frag row)
            const int m  = mb + mr;
            const float y = (acc[r] + bv + agg[(m << 8) + n] * norm[m]) * s2;
            const float sig = 1.f / (1.f + __expf(-y));
            h_s[mr][n] = f2bf(GAIN_F * y * sig);
        }
    }
    __syncthreads();

    // ---------------- gemm2 (this block's quadrant; waves 0..3) -------
    if (w < 4) {
        bf16x8 a2[8];                               // row = c, k = q*32+g*8+b
        #pragma unroll
        for (int q = 0; q < 8; ++q)
            a2[q] = *(const bf16x8*)(&h_s[c][(q << 5) + (g << 3)]);

        const int ct = (qd << 2) + w;               // col-tile 0..15, unique
        const short* bb = w2f + (ct << 12) + (lane << 3);
        bf16x8 b[8];
        #pragma unroll
        for (int q = 0; q < 8; ++q) b[q] = *(const bf16x8*)(bb + (q << 9));
        f32x4 acc = {0.f, 0.f, 0.f, 0.f};
        #pragma unroll
        for (int q = 0; q < 8; ++q)
            acc = __builtin_amdgcn_mfma_f32_16x16x32_bf16(a2[q], b[q], acc, 0, 0, 0);

        const int n  = (ct << 4) + c;
        const float bv = b2[n];
        #pragma unroll
        for (int r = 0; r < 4; ++r) {
            const int m = mb + (g << 2) + r;
            const float z = acc[r] + bv;
            const float sig = 1.f / (1.f + __expf(-z));
            const float o = GAIN_F * z * sig;
            outp[(m << 8) + n] = (elec[(m << 8) + n] + o) * INV_SQRT2_F;
        }
    }
}

// ---------------------------------------------------------------------------
extern "C" void kernel_launch(void* const* d_in, const int* in_sizes, int n_in,
                              void* d_out, int out_size, void* d_ws, size_t ws_size,
                              hipStream_t stream)
{
    const float* elec  = (const float*)d_in[0];
    const float* up    = (const float*)d_in[1];
    const float* dn    = (const float*)d_in[2];
    const float* eemb  = (const float*)d_in[3];
    // d_in[4] = contr: init-time only, unused at runtime
    const float* norm  = (const float*)d_in[5];
    const float* W1    = (const float*)d_in[6];
    const float* b1    = (const float*)d_in[7];
    const float* Wedge = (const float*)d_in[8];
    const float* W2    = (const float*)d_in[9];
    const float* b2    = (const float*)d_in[10];
    const float* s1    = (const float*)d_in[11];
    const float* s2    = (const float*)d_in[12];

    // ws layout (shorts): w1f 65536 | w2f 65536 | elecb 262144 |
    //   Tf 4194304 | P f32 8x262144 (8 MB) | agg f32 262144 (1 MB)
    short* sbase = (short*)d_ws;
    short* w1f   = sbase;
    short* w2f   = sbase + 65536;
    short* elecb = sbase + 131072;
    short* Tf    = sbase + 393216;
    float* P     = (float*)(sbase + 393216 + 4194304);
    float* agg   = P + (size_t)NKP * 262144;

    prep_kernel  <<<2048, 256, 0, stream>>>(up, dn, Wedge, W1, W2, elec,
                                            w1f, w2f, elecb, Tf);
    edge_gemm    <<<256, 512, 0, stream>>>(eemb, Tf, P);
    reduce_kernel<<<256, 256, 0, stream>>>(P, s1, agg);
    out_kernel   <<<256, 512, 0, stream>>>(elecb, w1f, w2f, elec, agg, norm,
                                           b1, b2, s2, (float*)d_out);
}